// Round 3
// baseline (2976.656 us; speedup 1.0000x reference)
//
#include <hip/hip_runtime.h>

typedef unsigned short u16;
typedef unsigned int u32;

// ---------- bf16 helpers ----------
__device__ __forceinline__ float b2f(u16 v) { return __uint_as_float(((u32)v) << 16); }
__device__ __forceinline__ u16 f2b(float f) {   // round-to-nearest-even
    u32 x = __float_as_uint(f);
    return (u16)((x + 0x7fffu + ((x >> 16) & 1u)) >> 16);
}
__device__ __forceinline__ float lo16(u32 w) { return __uint_as_float(w << 16); }
__device__ __forceinline__ float hi16(u32 w) { return __uint_as_float(w & 0xffff0000u); }
__device__ __forceinline__ void unpack8(uint4 u, float* f) {
    f[0] = lo16(u.x); f[1] = hi16(u.x);
    f[2] = lo16(u.y); f[3] = hi16(u.y);
    f[4] = lo16(u.z); f[5] = hi16(u.z);
    f[6] = lo16(u.w); f[7] = hi16(u.w);
}

#define S_LEN 256
#define B_SZ  512
#define DM    128
#define DFF   512
#define MROWS (S_LEN * B_SZ)   // 131072

// ================= dtype detect =================
// Scans emb (16384 elems). fp32 storage of bf16-rounded values -> low16==0
// everywhere; full-precision fp32 -> low16 uniform (many huge bf16 exponents);
// true packed bf16 -> low16 are small-exponent bf16 values, rarely exact 0.
__global__ __launch_bounds__(256) void detect_kernel(const u32* __restrict__ embw,
                                                     int* __restrict__ flag) {
    int z = 0, big = 0;
    for (int i = threadIdx.x; i < 8192; i += 256) {
        u32 w = embw[i];
        u32 lo = w & 0xffffu;
        if (lo == 0u) z++;
        else if (((lo >> 7) & 0xffu) >= 0xC0u) big++;
    }
#pragma unroll
    for (int off = 32; off > 0; off >>= 1) {
        z   += __shfl_xor(z, off, 64);
        big += __shfl_xor(big, off, 64);
    }
    __shared__ int zz[4], bb[4];
    if ((threadIdx.x & 63) == 0) { zz[threadIdx.x >> 6] = z; bb[threadIdx.x >> 6] = big; }
    __syncthreads();
    if (threadIdx.x == 0) {
        int Z = zz[0] + zz[1] + zz[2] + zz[3];
        int Bc = bb[0] + bb[1] + bb[2] + bb[3];
        flag[0] = (Z > 4096 || Bc > 16) ? 1 : 0;   // 1 = fp32 storage
    }
}

// ================= convert all float inputs -> canonical bf16 =================
struct Ptrs { const void* p[17]; };

__global__ __launch_bounds__(256) void convert_kernel(Ptrs ps, u16* __restrict__ canon,
                                                      const int* __restrict__ flag) {
    const int cnt[17] = {16384,32768,256,32768,256,32768,256,131072,1024,131072,
                         256,256,256,256,256,1280,10};
    const int off[17] = {0,16384,49152,49408,82176,82432,115200,115456,246528,
                         247552,378624,378880,379136,379392,379648,379904,381184};
    const int bst[18] = {0,8,24,25,41,42,58,59,123,124,188,189,190,191,192,193,194,195};
    const int isf = *flag;
    const int blk = blockIdx.x;
    int idx = 0;
#pragma unroll
    for (int i = 0; i < 17; ++i) if (blk >= bst[i + 1]) idx = i + 1;
    const int local = blk - bst[idx];
    const int n = cnt[idx];
    const void* sp = ps.p[idx];
    u16* dp = canon + off[idx];
#pragma unroll
    for (int j = 0; j < 8; ++j) {
        int e = local * 2048 + j * 256 + threadIdx.x;
        if (e < n) {
            u16 v = isf ? f2b(((const float*)sp)[e]) : ((const u16*)sp)[e];
            dp[e] = v;
        }
    }
}

// ================= embed + positional encoding → X bf16 =================
__global__ __launch_bounds__(256) void embed_kernel(const int* __restrict__ src,
                                                    const u16* __restrict__ emb,
                                                    u16* __restrict__ X) {
    int idx = blockIdx.x * 256 + threadIdx.x;      // one per bf16 pair
    int d2 = idx & 63;
    int m = idx >> 6;              // s*512 + b
    int s = m >> 9;
    int b = m & 511;
    int tok = src[b * S_LEN + s];
    int d = d2 * 2;
    float e0 = b2f(emb[tok * DM + d])     * 11.3137084989847604f; // sqrt(128)
    float e1 = b2f(emb[tok * DM + d + 1]) * 11.3137084989847604f;
    float ang = (float)s * expf((float)d * -0.0719557841560639f); // -ln(10000)/128
    float v0 = e0 + sinf(ang);
    float v1 = e1 + cosf(ang);
    u32 w = (u32)f2b(v0) | ((u32)f2b(v1) << 16);
    *(u32*)(X + (size_t)m * DM + d) = w;
}

// ================= per-s fused K/V projection + KV + Ksum =================
__global__ __launch_bounds__(256) void kvproj_kernel(
    const u16* __restrict__ X, const u16* __restrict__ Wk, const u16* __restrict__ bk,
    const u16* __restrict__ Wv, const u16* __restrict__ bv,
    float* __restrict__ KV, float* __restrict__ Ksum)
{
    __shared__ __align__(16) char sm_[65536];
    u16*   WkL = (u16*)sm_;               // 32KB [e][k], 16-slot xor swizzle
    u16*   WvL = (u16*)(sm_ + 32768);     // 16KB
    u16*   Xc  = (u16*)(sm_ + 49152);     // 4KB  16 rows
    float* Kc  = (float*)(sm_ + 53248);   // 8KB  16x128
    float* Vc  = (float*)(sm_ + 61440);   // 4KB  16x64
    const int blk = blockIdx.x, s = blk >> 1, eh = blk & 1, t = threadIdx.x;

#pragma unroll
    for (int i = 0; i < 8; ++i) {
        int e = (i * 256 + t) * 8; int r = e >> 7, k0 = e & 127, sl = k0 >> 3;
        *(uint4*)(WkL + r * 128 + (((sl ^ (r & 15)) & 15) << 3)) = *(const uint4*)(Wk + e);
    }
#pragma unroll
    for (int i = 0; i < 4; ++i) {
        int e = (i * 256 + t) * 8; int r = e >> 7, k0 = e & 127, sl = k0 >> 3;
        *(uint4*)(WvL + r * 128 + (((sl ^ (r & 15)) & 15) << 3)) =
            *(const uint4*)(Wv + (size_t)eh * 64 * 128 + e);
    }
    float acc[8][4] = {};
    float ks = 0.f;
    const int d0 = (t >> 4) * 8, e0 = (t & 15) * 4;
    const int rr = t >> 5, ee = t & 31;
    const u16* Xg = X + (size_t)s * B_SZ * DM;
    float kb4[4], vb2[2];
#pragma unroll
    for (int j = 0; j < 4; ++j) kb4[j] = b2f(bk[ee * 4 + j]);
#pragma unroll
    for (int j = 0; j < 2; ++j) vb2[j] = b2f(bv[eh * 64 + ee * 2 + j]);
    __syncthreads();

    for (int b0 = 0; b0 < B_SZ; b0 += 16) {
        { int e = t * 8; int r = e >> 7, k0 = e & 127, sl = k0 >> 3;
          *(uint4*)(Xc + r * 128 + (((sl ^ (r & 15)) & 15) << 3)) =
              *(const uint4*)(Xg + (size_t)(b0 + r) * DM + k0); }
        __syncthreads();
        float ka[2][4] = {}, va[2][2] = {};
#pragma unroll 4
        for (int k8 = 0; k8 < 16; ++k8) {
            float xf[2][8];
#pragma unroll
            for (int i = 0; i < 2; ++i) {
                int r = rr * 2 + i;
                uint4 u = *(const uint4*)(Xc + r * 128 + (((k8 ^ (r & 15)) & 15) << 3));
                unpack8(u, xf[i]);
            }
#pragma unroll
            for (int j = 0; j < 4; ++j) {
                int c = ee * 4 + j;
                uint4 u = *(const uint4*)(WkL + c * 128 + (((k8 ^ (c & 15)) & 15) << 3));
                float wf[8]; unpack8(u, wf);
#pragma unroll
                for (int i = 0; i < 2; ++i)
#pragma unroll
                    for (int kk = 0; kk < 8; ++kk)
                        ka[i][j] = fmaf(xf[i][kk], wf[kk], ka[i][j]);
            }
#pragma unroll
            for (int j = 0; j < 2; ++j) {
                int c = ee * 2 + j;
                uint4 u = *(const uint4*)(WvL + c * 128 + (((k8 ^ (c & 15)) & 15) << 3));
                float wf[8]; unpack8(u, wf);
#pragma unroll
                for (int i = 0; i < 2; ++i)
#pragma unroll
                    for (int kk = 0; kk < 8; ++kk)
                        va[i][j] = fmaf(xf[i][kk], wf[kk], va[i][j]);
            }
        }
#pragma unroll
        for (int i = 0; i < 2; ++i)
#pragma unroll
            for (int j = 0; j < 4; ++j)
                Kc[(rr * 2 + i) * 128 + ee * 4 + j] = fmaxf(ka[i][j] + kb4[j], 0.f) + 1e-6f;
#pragma unroll
        for (int i = 0; i < 2; ++i)
#pragma unroll
            for (int j = 0; j < 2; ++j)
                Vc[(rr * 2 + i) * 64 + ee * 2 + j] = va[i][j] + vb2[j];
        __syncthreads();
        if (eh == 0 && t < 128) {
#pragma unroll
            for (int bb = 0; bb < 16; ++bb) ks += Kc[bb * 128 + t];
        }
#pragma unroll 4
        for (int bb = 0; bb < 16; ++bb) {
            float4 k0v = *(const float4*)(Kc + bb * 128 + d0);
            float4 k1v = *(const float4*)(Kc + bb * 128 + d0 + 4);
            float4 vv  = *(const float4*)(Vc + bb * 64 + e0);
            float a8[8] = {k0v.x, k0v.y, k0v.z, k0v.w, k1v.x, k1v.y, k1v.z, k1v.w};
            float b4[4] = {vv.x, vv.y, vv.z, vv.w};
#pragma unroll
            for (int i = 0; i < 8; ++i)
#pragma unroll
                for (int j = 0; j < 4; ++j)
                    acc[i][j] = fmaf(a8[i], b4[j], acc[i][j]);
        }
        __syncthreads();
    }
    float* KVb = KV + (size_t)s * (DM * DM) + eh * 64;
#pragma unroll
    for (int i = 0; i < 8; ++i)
        *(float4*)(KVb + (size_t)(d0 + i) * 128 + e0) =
            make_float4(acc[i][0], acc[i][1], acc[i][2], acc[i][3]);
    if (eh == 0 && t < 128) Ksum[s * 128 + t] = ks;
}

// ================= fused Q-proj + attn + residual + LN =================
__global__ __launch_bounds__(256) void attn_ln_kernel(
    const u16* Xg, const u16* __restrict__ Wq, const u16* __restrict__ bq,
    const float* __restrict__ KV, const float* __restrict__ Ksum,
    u16* Xout, const u16* __restrict__ g, const u16* __restrict__ beta)
{
    __shared__ __align__(16) char sm_[64256];
    u16*   WqL    = (u16*)sm_;               // 32KB (aliased by zs later)
    u16*   Xc     = (u16*)(sm_ + 32768);     // 8KB
    float* qsT    = (float*)(sm_ + 40960);   // 18KB [d][r] stride 36
    float* KVs    = (float*)(sm_ + 59392);   // 4.2KB 8x132
    float* ksum_s = (float*)(sm_ + 63616);
    float* zden   = (float*)(sm_ + 64128);
    float* zs     = (float*)sm_;
    const int blk = blockIdx.x, s = blk >> 4, b0 = (blk & 15) * 32, t = threadIdx.x;
    const size_t m0 = (size_t)s * B_SZ + b0;

#pragma unroll
    for (int i = 0; i < 8; ++i) {
        int e = (i * 256 + t) * 8; int r = e >> 7, k0 = e & 127, sl = k0 >> 3;
        *(uint4*)(WqL + r * 128 + (((sl ^ (r & 15)) & 15) << 3)) = *(const uint4*)(Wq + e);
    }
#pragma unroll
    for (int i = 0; i < 2; ++i) {
        int e = (i * 256 + t) * 8; int r = e >> 7, k0 = e & 127, sl = k0 >> 3;
        *(uint4*)(Xc + r * 128 + (((sl ^ (r & 15)) & 15) << 3)) =
            *(const uint4*)(Xg + (m0 + r) * DM + k0);
    }
    if (t < 128) ksum_s[t] = Ksum[s * 128 + t];
    const int rr = t >> 5, ee = t & 31;
    float qb4[4];
#pragma unroll
    for (int j = 0; j < 4; ++j) qb4[j] = b2f(bq[ee * 4 + j]);
    __syncthreads();

    float qa[4][4] = {};
#pragma unroll 4
    for (int k8 = 0; k8 < 16; ++k8) {
        float xf[4][8];
#pragma unroll
        for (int i = 0; i < 4; ++i) {
            int r = rr * 4 + i;
            uint4 u = *(const uint4*)(Xc + r * 128 + (((k8 ^ (r & 15)) & 15) << 3));
            unpack8(u, xf[i]);
        }
#pragma unroll
        for (int j = 0; j < 4; ++j) {
            int c = ee * 4 + j;
            uint4 u = *(const uint4*)(WqL + c * 128 + (((k8 ^ (c & 15)) & 15) << 3));
            float wf[8]; unpack8(u, wf);
#pragma unroll
            for (int i = 0; i < 4; ++i)
#pragma unroll
                for (int kk = 0; kk < 8; ++kk)
                    qa[i][j] = fmaf(xf[i][kk], wf[kk], qa[i][j]);
        }
    }
#pragma unroll
    for (int i = 0; i < 4; ++i)
#pragma unroll
        for (int j = 0; j < 4; ++j)
            qsT[(ee * 4 + j) * 36 + rr * 4 + i] = fmaxf(qa[i][j] + qb4[j], 0.f) + 1e-6f;
    __syncthreads();
    if (t < 32) {
        float a = 0.f;
        for (int d = 0; d < 128; ++d) a = fmaf(qsT[d * 36 + t], ksum_s[d], a);
        zden[t] = 1.f / (a + 1e-6f);
    }

    const int e4 = (t & 31) * 4, rg = t >> 5;
    float acc2[4][4] = {};
    const float* KVb = KV + (size_t)s * (DM * DM);
    for (int dc = 0; dc < 128; dc += 8) {
        __syncthreads();
        { int e = t * 4; int dd = e >> 7, c2 = e & 127;
          *(float4*)(KVs + dd * 132 + c2) = *(const float4*)(KVb + (size_t)(dc + dd) * 128 + c2); }
        __syncthreads();
#pragma unroll
        for (int dd = 0; dd < 8; ++dd) {
            float4 q4 = *(const float4*)(qsT + (dc + dd) * 36 + rg * 4);
            float4 kv = *(const float4*)(KVs + dd * 132 + e4);
            float qa4[4] = {q4.x, q4.y, q4.z, q4.w};
            float kb[4]  = {kv.x, kv.y, kv.z, kv.w};
#pragma unroll
            for (int i = 0; i < 4; ++i)
#pragma unroll
                for (int j = 0; j < 4; ++j)
                    acc2[i][j] = fmaf(qa4[i], kb[j], acc2[i][j]);
        }
    }
#pragma unroll
    for (int i = 0; i < 4; ++i) {
        int r = rg * 4 + i; float z = zden[r];
        uint2 xr = *(const uint2*)(Xg + (m0 + r) * DM + e4);
        zs[r * 132 + e4 + 0] = fmaf(acc2[i][0], z, lo16(xr.x));
        zs[r * 132 + e4 + 1] = fmaf(acc2[i][1], z, hi16(xr.x));
        zs[r * 132 + e4 + 2] = fmaf(acc2[i][2], z, lo16(xr.y));
        zs[r * 132 + e4 + 3] = fmaf(acc2[i][3], z, hi16(xr.y));
    }
    __syncthreads();
    int wv = t >> 6, ln = t & 63;
    float g0 = b2f(g[ln]), g1v = b2f(g[64 + ln]);
    float be0 = b2f(beta[ln]), be1 = b2f(beta[64 + ln]);
#pragma unroll
    for (int q = 0; q < 8; ++q) {
        int r = wv * 8 + q;
        float v0 = zs[r * 132 + ln], v1 = zs[r * 132 + 64 + ln];
        float sum = v0 + v1, sq = v0 * v0 + v1 * v1;
#pragma unroll
        for (int off = 32; off > 0; off >>= 1) {
            sum += __shfl_xor(sum, off, 64);
            sq  += __shfl_xor(sq,  off, 64);
        }
        float mean = sum * 0.0078125f;
        float var  = sq * 0.0078125f - mean * mean;
        float rstd = rsqrtf(fmaxf(var, 0.f) + 1e-5f);
        Xout[(m0 + r) * DM + ln]      = f2b((v0 - mean) * rstd * g0  + be0);
        Xout[(m0 + r) * DM + 64 + ln] = f2b((v1 - mean) * rstd * g1v + be1);
    }
}

// ================= fused MLP: relu(X W1^T + b1) W2^T + b2 + X → LN =================
__global__ __launch_bounds__(256) void mlp_kernel(
    const u16* X, const u16* __restrict__ W1, const u16* __restrict__ b1,
    const u16* __restrict__ W2, const u16* __restrict__ b2,
    u16* Xout, const u16* __restrict__ g, const u16* __restrict__ beta)
{
    __shared__ __align__(16) char sm_[65536];
    u16* As  = (u16*)sm_;             // 32KB [r][k]
    u16* W1c = (u16*)(sm_ + 32768);   // 16KB
    u16* Hc  = W1c;                   // aliases W1c
    u16* W2c = (u16*)(sm_ + 49152);   // 16KB
    float* zs = (float*)sm_;          // 64KB (epilogue only)
    const int t = threadIdx.x;
    const int m0 = blockIdx.x * 128;
    const int tr = t >> 4, tc = t & 15;

#pragma unroll
    for (int i = 0; i < 8; ++i) {
        int e = (i * 256 + t) * 8; int r = e >> 7, k0 = e & 127, sl = k0 >> 3;
        *(uint4*)(As + r * 128 + (((sl ^ (r & 15)) & 15) << 3)) =
            *(const uint4*)(X + (size_t)(m0 + r) * DM + k0);
    }
    float zacc[8][8] = {};
    for (int fc = 0; fc < DFF; fc += 64) {
        __syncthreads();
#pragma unroll
        for (int i = 0; i < 4; ++i) {
            int e = (i * 256 + t) * 8; int c = e >> 7, k0 = e & 127, sl = k0 >> 3;
            *(uint4*)(W1c + c * 128 + (((sl ^ (c & 15)) & 15) << 3)) =
                *(const uint4*)(W1 + (size_t)(fc + c) * DM + k0);
        }
#pragma unroll
        for (int i = 0; i < 4; ++i) {
            int e = (i * 256 + t) * 8; int d = e >> 6, f0 = e & 63, sl = f0 >> 3;
            *(uint4*)(W2c + d * 64 + (((sl ^ (d & 7)) & 7) << 3)) =
                *(const uint4*)(W2 + (size_t)d * DFF + fc + f0);
        }
        __syncthreads();
        float hacc[8][4] = {};
#pragma unroll 2
        for (int k8 = 0; k8 < 16; ++k8) {
            float af[8][8];
#pragma unroll
            for (int i = 0; i < 8; ++i) {
                int r = tr * 8 + i;
                uint4 u = *(const uint4*)(As + r * 128 + (((k8 ^ (r & 15)) & 15) << 3));
                unpack8(u, af[i]);
            }
#pragma unroll
            for (int j = 0; j < 4; ++j) {
                int c = tc * 4 + j;
                uint4 u = *(const uint4*)(W1c + c * 128 + (((k8 ^ (c & 15)) & 15) << 3));
                float wf[8]; unpack8(u, wf);
#pragma unroll
                for (int i = 0; i < 8; ++i)
#pragma unroll
                    for (int kk = 0; kk < 8; ++kk)
                        hacc[i][j] = fmaf(af[i][kk], wf[kk], hacc[i][j]);
            }
        }
        float hb[4];
#pragma unroll
        for (int j = 0; j < 4; ++j) hb[j] = b2f(b1[fc + tc * 4 + j]);
        __syncthreads();
#pragma unroll
        for (int i = 0; i < 8; ++i) {
            int r = tr * 8 + i;
            u16 h0 = f2b(fmaxf(hacc[i][0] + hb[0], 0.f));
            u16 h1 = f2b(fmaxf(hacc[i][1] + hb[1], 0.f));
            u16 h2 = f2b(fmaxf(hacc[i][2] + hb[2], 0.f));
            u16 h3 = f2b(fmaxf(hacc[i][3] + hb[3], 0.f));
            uint2 pk; pk.x = (u32)h0 | ((u32)h1 << 16); pk.y = (u32)h2 | ((u32)h3 << 16);
            int sl = tc >> 1, hf = tc & 1;
            *(uint2*)(Hc + r * 64 + (((sl ^ (r & 7)) & 7) << 3) + hf * 4) = pk;
        }
        __syncthreads();
#pragma unroll 2
        for (int f8 = 0; f8 < 8; ++f8) {
            float af[8][8];
#pragma unroll
            for (int i = 0; i < 8; ++i) {
                int r = tr * 8 + i;
                uint4 u = *(const uint4*)(Hc + r * 64 + (((f8 ^ (r & 7)) & 7) << 3));
                unpack8(u, af[i]);
            }
#pragma unroll
            for (int j = 0; j < 8; ++j) {
                int d = tc * 8 + j;
                uint4 u = *(const uint4*)(W2c + d * 64 + (((f8 ^ (d & 7)) & 7) << 3));
                float wf[8]; unpack8(u, wf);
#pragma unroll
                for (int i = 0; i < 8; ++i)
#pragma unroll
                    for (int kk = 0; kk < 8; ++kk)
                        zacc[i][j] = fmaf(af[i][kk], wf[kk], zacc[i][j]);
            }
        }
    }
    __syncthreads();
    float bvv[8];
#pragma unroll
    for (int j = 0; j < 8; ++j) bvv[j] = b2f(b2[tc * 8 + j]);
#pragma unroll
    for (int i = 0; i < 8; ++i) {
        int r = tr * 8 + i;
        uint4 xr = *(const uint4*)(X + (size_t)(m0 + r) * DM + tc * 8);
        float xf[8]; unpack8(xr, xf);
#pragma unroll
        for (int j = 0; j < 8; ++j)
            zs[r * 128 + tc * 8 + j] = zacc[i][j] + bvv[j] + xf[j];
    }
    __syncthreads();
    int wv = t >> 6, ln = t & 63;
    float g0 = b2f(g[ln]), g1v = b2f(g[64 + ln]);
    float be0 = b2f(beta[ln]), be1 = b2f(beta[64 + ln]);
    for (int q = 0; q < 32; ++q) {
        int r = wv * 32 + q;
        float v0 = zs[r * 128 + ln], v1 = zs[r * 128 + 64 + ln];
        float sum = v0 + v1, sq = v0 * v0 + v1 * v1;
#pragma unroll
        for (int off = 32; off > 0; off >>= 1) {
            sum += __shfl_xor(sum, off, 64);
            sq  += __shfl_xor(sq,  off, 64);
        }
        float mean = sum * 0.0078125f;
        float var  = sq * 0.0078125f - mean * mean;
        float rstd = rsqrtf(fmaxf(var, 0.f) + 1e-5f);
        Xout[(size_t)(m0 + r) * DM + ln]      = f2b((v0 - mean) * rstd * g0  + be0);
        Xout[(size_t)(m0 + r) * DM + 64 + ln] = f2b((v1 - mean) * rstd * g1v + be1);
    }
}

// ================= mean over S + final FC (flag-dependent output dtype) ========
__global__ __launch_bounds__(128) void pool_fc_kernel(
    const u16* __restrict__ X, const u16* __restrict__ fcw,
    const u16* __restrict__ fcb, void* __restrict__ Out,
    const int* __restrict__ flag)
{
    __shared__ float pool[128];
    const int b = blockIdx.x, t = threadIdx.x;
    float acc = 0.f;
    for (int s = 0; s < S_LEN; ++s)
        acc += b2f(X[((size_t)s * B_SZ + b) * DM + t]);
    pool[t] = acc * (1.0f / 256.0f);
    __syncthreads();
    if (t < 10) {
        float o = b2f(fcb[t]);
        for (int d = 0; d < 128; ++d) o += pool[d] * b2f(fcw[t * 128 + d]);
        if (*flag) ((float*)Out)[b * 10 + t] = o;
        else       ((u16*)Out)[b * 10 + t] = f2b(o);
    }
}

// ================= launch =================
extern "C" void kernel_launch(void* const* d_in, const int* in_sizes, int n_in,
                              void* d_out, int out_size, void* d_ws, size_t ws_size,
                              hipStream_t stream)
{
    const int* src = (const int*)d_in[0];

    // ws layout (bytes):
    //   X bf16        : 0          .. 33,554,432
    //   KV fp32       : 33,554,432 .. 50,331,648
    //   Ksum fp32     : 50,331,648 .. 50,462,720
    //   flag int      : 50,462,720
    //   canon bf16    : 50,462,976 .. ~51.3 MB
    char* ws = (char*)d_ws;
    u16*   X    = (u16*)ws;
    float* KV   = (float*)(ws + 33554432);
    float* Ksum = (float*)(ws + 50331648);
    int*   flag = (int*)(ws + 50462720);
    u16*   cn   = (u16*)(ws + 50462976);

    // canonical bf16 offsets (elements)
    u16* emb = cn + 0;
    u16* wq  = cn + 16384;
    u16* bq  = cn + 49152;
    u16* wk  = cn + 49408;
    u16* bk  = cn + 82176;
    u16* wv  = cn + 82432;
    u16* bvp = cn + 115200;
    u16* w1  = cn + 115456;
    u16* b1  = cn + 246528;
    u16* w2  = cn + 247552;
    u16* b2  = cn + 378624;
    u16* g1  = cn + 378880;
    u16* be1 = cn + 379136;
    u16* g2  = cn + 379392;
    u16* be2 = cn + 379648;
    u16* fcw = cn + 379904;
    u16* fcb = cn + 381184;

    detect_kernel<<<1, 256, 0, stream>>>((const u32*)d_in[1], flag);

    Ptrs ps;
    for (int i = 0; i < 17; ++i) ps.p[i] = d_in[i + 1];
    convert_kernel<<<195, 256, 0, stream>>>(ps, cn, flag);

    embed_kernel<<<MROWS * 64 / 256, 256, 0, stream>>>(src, emb, X);

    for (int l = 0; l < 2; ++l) {
        kvproj_kernel<<<S_LEN * 2, 256, 0, stream>>>(
            X, wk + l * DM * DM, bk + l * DM, wv + l * DM * DM, bvp + l * DM, KV, Ksum);
        attn_ln_kernel<<<S_LEN * 16, 256, 0, stream>>>(
            X, wq + l * DM * DM, bq + l * DM, KV, Ksum, X, g1 + l * DM, be1 + l * DM);
        mlp_kernel<<<MROWS / 128, 256, 0, stream>>>(
            X, w1 + l * DFF * DM, b1 + l * DFF, w2 + l * DM * DFF, b2 + l * DM,
            X, g2 + l * DM, be2 + l * DM);
    }

    pool_fc_kernel<<<B_SZ, 128, 0, stream>>>(X, fcw, fcb, d_out, flag);
}

// Round 4
// 1632.740 us; speedup vs baseline: 1.8231x; 1.8231x over previous
//
#include <hip/hip_runtime.h>

typedef unsigned short u16;
typedef unsigned int u32;
typedef short bf16x8 __attribute__((ext_vector_type(8)));
typedef float f32x4 __attribute__((ext_vector_type(4)));

// ---------- bf16 helpers ----------
__device__ __forceinline__ float b2f(u16 v) { return __uint_as_float(((u32)v) << 16); }
__device__ __forceinline__ u16 f2b(float f) {   // round-to-nearest-even
    u32 x = __float_as_uint(f);
    return (u16)((x + 0x7fffu + ((x >> 16) & 1u)) >> 16);
}
__device__ __forceinline__ float lo16(u32 w) { return __uint_as_float(w << 16); }
__device__ __forceinline__ float hi16(u32 w) { return __uint_as_float(w & 0xffff0000u); }
__device__ __forceinline__ void unpack8(uint4 u, float* f) {
    f[0] = lo16(u.x); f[1] = hi16(u.x);
    f[2] = lo16(u.y); f[3] = hi16(u.y);
    f[4] = lo16(u.z); f[5] = hi16(u.z);
    f[6] = lo16(u.w); f[7] = hi16(u.w);
}

#define S_LEN 256
#define B_SZ  512
#define DM    128
#define DFF   512
#define MROWS (S_LEN * B_SZ)   // 131072

// ================= dtype detect =================
__global__ __launch_bounds__(256) void detect_kernel(const u32* __restrict__ embw,
                                                     int* __restrict__ flag) {
    int z = 0, big = 0;
    for (int i = threadIdx.x; i < 8192; i += 256) {
        u32 w = embw[i];
        u32 lo = w & 0xffffu;
        if (lo == 0u) z++;
        else if (((lo >> 7) & 0xffu) >= 0xC0u) big++;
    }
#pragma unroll
    for (int off = 32; off > 0; off >>= 1) {
        z   += __shfl_xor(z, off, 64);
        big += __shfl_xor(big, off, 64);
    }
    __shared__ int zz[4], bb[4];
    if ((threadIdx.x & 63) == 0) { zz[threadIdx.x >> 6] = z; bb[threadIdx.x >> 6] = big; }
    __syncthreads();
    if (threadIdx.x == 0) {
        int Z = zz[0] + zz[1] + zz[2] + zz[3];
        int Bc = bb[0] + bb[1] + bb[2] + bb[3];
        flag[0] = (Z > 4096 || Bc > 16) ? 1 : 0;   // 1 = fp32 storage
    }
}

// ================= convert all float inputs -> canonical bf16 =================
struct Ptrs { const void* p[17]; };

__global__ __launch_bounds__(256) void convert_kernel(Ptrs ps, u16* __restrict__ canon,
                                                      const int* __restrict__ flag) {
    const int cnt[17] = {16384,32768,256,32768,256,32768,256,131072,1024,131072,
                         256,256,256,256,256,1280,10};
    const int off[17] = {0,16384,49152,49408,82176,82432,115200,115456,246528,
                         247552,378624,378880,379136,379392,379648,379904,381184};
    const int bst[18] = {0,8,24,25,41,42,58,59,123,124,188,189,190,191,192,193,194,195};
    const int isf = *flag;
    const int blk = blockIdx.x;
    int idx = 0;
#pragma unroll
    for (int i = 0; i < 17; ++i) if (blk >= bst[i + 1]) idx = i + 1;
    const int local = blk - bst[idx];
    const int n = cnt[idx];
    const void* sp = ps.p[idx];
    u16* dp = canon + off[idx];
#pragma unroll
    for (int j = 0; j < 8; ++j) {
        int e = local * 2048 + j * 256 + threadIdx.x;
        if (e < n) {
            u16 v = isf ? f2b(((const float*)sp)[e]) : ((const u16*)sp)[e];
            dp[e] = v;
        }
    }
}

// ================= embed + positional encoding → X bf16 =================
__global__ __launch_bounds__(256) void embed_kernel(const int* __restrict__ src,
                                                    const u16* __restrict__ emb,
                                                    u16* __restrict__ X) {
    int idx = blockIdx.x * 256 + threadIdx.x;      // one per bf16 pair
    int d2 = idx & 63;
    int m = idx >> 6;              // s*512 + b
    int s = m >> 9;
    int b = m & 511;
    int tok = src[b * S_LEN + s];
    int d = d2 * 2;
    float e0 = b2f(emb[tok * DM + d])     * 11.3137084989847604f; // sqrt(128)
    float e1 = b2f(emb[tok * DM + d + 1]) * 11.3137084989847604f;
    float ang = (float)s * expf((float)d * -0.0719557841560639f); // -ln(10000)/128
    float v0 = e0 + sinf(ang);
    float v1 = e1 + cosf(ang);
    u32 w = (u32)f2b(v0) | ((u32)f2b(v1) << 16);
    *(u32*)(X + (size_t)m * DM + d) = w;
}

// ================= per-s fused K/V projection + KV + Ksum =================
__global__ __launch_bounds__(256) void kvproj_kernel(
    const u16* __restrict__ X, const u16* __restrict__ Wk, const u16* __restrict__ bk,
    const u16* __restrict__ Wv, const u16* __restrict__ bv,
    float* __restrict__ KV, float* __restrict__ Ksum)
{
    __shared__ __align__(16) char sm_[65536];
    u16*   WkL = (u16*)sm_;               // 32KB [e][k], 16-slot xor swizzle
    u16*   WvL = (u16*)(sm_ + 32768);     // 16KB
    u16*   Xc  = (u16*)(sm_ + 49152);     // 4KB  16 rows
    float* Kc  = (float*)(sm_ + 53248);   // 8KB  16x128
    float* Vc  = (float*)(sm_ + 61440);   // 4KB  16x64
    const int blk = blockIdx.x, s = blk >> 1, eh = blk & 1, t = threadIdx.x;

#pragma unroll
    for (int i = 0; i < 8; ++i) {
        int e = (i * 256 + t) * 8; int r = e >> 7, k0 = e & 127, sl = k0 >> 3;
        *(uint4*)(WkL + r * 128 + (((sl ^ (r & 15)) & 15) << 3)) = *(const uint4*)(Wk + e);
    }
#pragma unroll
    for (int i = 0; i < 4; ++i) {
        int e = (i * 256 + t) * 8; int r = e >> 7, k0 = e & 127, sl = k0 >> 3;
        *(uint4*)(WvL + r * 128 + (((sl ^ (r & 15)) & 15) << 3)) =
            *(const uint4*)(Wv + (size_t)eh * 64 * 128 + e);
    }
    float acc[8][4] = {};
    float ks = 0.f;
    const int d0 = (t >> 4) * 8, e0 = (t & 15) * 4;
    const int rr = t >> 5, ee = t & 31;
    const u16* Xg = X + (size_t)s * B_SZ * DM;
    float kb4[4], vb2[2];
#pragma unroll
    for (int j = 0; j < 4; ++j) kb4[j] = b2f(bk[ee * 4 + j]);
#pragma unroll
    for (int j = 0; j < 2; ++j) vb2[j] = b2f(bv[eh * 64 + ee * 2 + j]);
    __syncthreads();

    for (int b0 = 0; b0 < B_SZ; b0 += 16) {
        { int e = t * 8; int r = e >> 7, k0 = e & 127, sl = k0 >> 3;
          *(uint4*)(Xc + r * 128 + (((sl ^ (r & 15)) & 15) << 3)) =
              *(const uint4*)(Xg + (size_t)(b0 + r) * DM + k0); }
        __syncthreads();
        float ka[2][4] = {}, va[2][2] = {};
#pragma unroll 4
        for (int k8 = 0; k8 < 16; ++k8) {
            float xf[2][8];
#pragma unroll
            for (int i = 0; i < 2; ++i) {
                int r = rr * 2 + i;
                uint4 u = *(const uint4*)(Xc + r * 128 + (((k8 ^ (r & 15)) & 15) << 3));
                unpack8(u, xf[i]);
            }
#pragma unroll
            for (int j = 0; j < 4; ++j) {
                int c = ee * 4 + j;
                uint4 u = *(const uint4*)(WkL + c * 128 + (((k8 ^ (c & 15)) & 15) << 3));
                float wf[8]; unpack8(u, wf);
#pragma unroll
                for (int i = 0; i < 2; ++i)
#pragma unroll
                    for (int kk = 0; kk < 8; ++kk)
                        ka[i][j] = fmaf(xf[i][kk], wf[kk], ka[i][j]);
            }
#pragma unroll
            for (int j = 0; j < 2; ++j) {
                int c = ee * 2 + j;
                uint4 u = *(const uint4*)(WvL + c * 128 + (((k8 ^ (c & 15)) & 15) << 3));
                float wf[8]; unpack8(u, wf);
#pragma unroll
                for (int i = 0; i < 2; ++i)
#pragma unroll
                    for (int kk = 0; kk < 8; ++kk)
                        va[i][j] = fmaf(xf[i][kk], wf[kk], va[i][j]);
            }
        }
#pragma unroll
        for (int i = 0; i < 2; ++i)
#pragma unroll
            for (int j = 0; j < 4; ++j)
                Kc[(rr * 2 + i) * 128 + ee * 4 + j] = fmaxf(ka[i][j] + kb4[j], 0.f) + 1e-6f;
#pragma unroll
        for (int i = 0; i < 2; ++i)
#pragma unroll
            for (int j = 0; j < 2; ++j)
                Vc[(rr * 2 + i) * 64 + ee * 2 + j] = va[i][j] + vb2[j];
        __syncthreads();
        if (eh == 0 && t < 128) {
#pragma unroll
            for (int bb = 0; bb < 16; ++bb) ks += Kc[bb * 128 + t];
        }
#pragma unroll 4
        for (int bb = 0; bb < 16; ++bb) {
            float4 k0v = *(const float4*)(Kc + bb * 128 + d0);
            float4 k1v = *(const float4*)(Kc + bb * 128 + d0 + 4);
            float4 vv  = *(const float4*)(Vc + bb * 64 + e0);
            float a8[8] = {k0v.x, k0v.y, k0v.z, k0v.w, k1v.x, k1v.y, k1v.z, k1v.w};
            float b4[4] = {vv.x, vv.y, vv.z, vv.w};
#pragma unroll
            for (int i = 0; i < 8; ++i)
#pragma unroll
                for (int j = 0; j < 4; ++j)
                    acc[i][j] = fmaf(a8[i], b4[j], acc[i][j]);
        }
        __syncthreads();
    }
    float* KVb = KV + (size_t)s * (DM * DM) + eh * 64;
#pragma unroll
    for (int i = 0; i < 8; ++i)
        *(float4*)(KVb + (size_t)(d0 + i) * 128 + e0) =
            make_float4(acc[i][0], acc[i][1], acc[i][2], acc[i][3]);
    if (eh == 0 && t < 128) Ksum[s * 128 + t] = ks;
}

// ================= fused Q-proj + attn + residual + LN =================
__global__ __launch_bounds__(256) void attn_ln_kernel(
    const u16* Xg, const u16* __restrict__ Wq, const u16* __restrict__ bq,
    const float* __restrict__ KV, const float* __restrict__ Ksum,
    u16* Xout, const u16* __restrict__ g, const u16* __restrict__ beta)
{
    __shared__ __align__(16) char sm_[64256];
    u16*   WqL    = (u16*)sm_;               // 32KB (aliased by zs later)
    u16*   Xc     = (u16*)(sm_ + 32768);     // 8KB
    float* qsT    = (float*)(sm_ + 40960);   // 18KB [d][r] stride 36
    float* KVs    = (float*)(sm_ + 59392);   // 4.2KB 8x132
    float* ksum_s = (float*)(sm_ + 63616);
    float* zden   = (float*)(sm_ + 64128);
    float* zs     = (float*)sm_;
    const int blk = blockIdx.x, s = blk >> 4, b0 = (blk & 15) * 32, t = threadIdx.x;
    const size_t m0 = (size_t)s * B_SZ + b0;

#pragma unroll
    for (int i = 0; i < 8; ++i) {
        int e = (i * 256 + t) * 8; int r = e >> 7, k0 = e & 127, sl = k0 >> 3;
        *(uint4*)(WqL + r * 128 + (((sl ^ (r & 15)) & 15) << 3)) = *(const uint4*)(Wq + e);
    }
#pragma unroll
    for (int i = 0; i < 2; ++i) {
        int e = (i * 256 + t) * 8; int r = e >> 7, k0 = e & 127, sl = k0 >> 3;
        *(uint4*)(Xc + r * 128 + (((sl ^ (r & 15)) & 15) << 3)) =
            *(const uint4*)(Xg + (m0 + r) * DM + k0);
    }
    if (t < 128) ksum_s[t] = Ksum[s * 128 + t];
    const int rr = t >> 5, ee = t & 31;
    float qb4[4];
#pragma unroll
    for (int j = 0; j < 4; ++j) qb4[j] = b2f(bq[ee * 4 + j]);
    __syncthreads();

    float qa[4][4] = {};
#pragma unroll 4
    for (int k8 = 0; k8 < 16; ++k8) {
        float xf[4][8];
#pragma unroll
        for (int i = 0; i < 4; ++i) {
            int r = rr * 4 + i;
            uint4 u = *(const uint4*)(Xc + r * 128 + (((k8 ^ (r & 15)) & 15) << 3));
            unpack8(u, xf[i]);
        }
#pragma unroll
        for (int j = 0; j < 4; ++j) {
            int c = ee * 4 + j;
            uint4 u = *(const uint4*)(WqL + c * 128 + (((k8 ^ (c & 15)) & 15) << 3));
            float wf[8]; unpack8(u, wf);
#pragma unroll
            for (int i = 0; i < 4; ++i)
#pragma unroll
                for (int kk = 0; kk < 8; ++kk)
                    qa[i][j] = fmaf(xf[i][kk], wf[kk], qa[i][j]);
        }
    }
#pragma unroll
    for (int i = 0; i < 4; ++i)
#pragma unroll
        for (int j = 0; j < 4; ++j)
            qsT[(ee * 4 + j) * 36 + rr * 4 + i] = fmaxf(qa[i][j] + qb4[j], 0.f) + 1e-6f;
    __syncthreads();
    if (t < 32) {
        float a = 0.f;
        for (int d = 0; d < 128; ++d) a = fmaf(qsT[d * 36 + t], ksum_s[d], a);
        zden[t] = 1.f / (a + 1e-6f);
    }

    const int e4 = (t & 31) * 4, rg = t >> 5;
    float acc2[4][4] = {};
    const float* KVb = KV + (size_t)s * (DM * DM);
    for (int dc = 0; dc < 128; dc += 8) {
        __syncthreads();
        { int e = t * 4; int dd = e >> 7, c2 = e & 127;
          *(float4*)(KVs + dd * 132 + c2) = *(const float4*)(KVb + (size_t)(dc + dd) * 128 + c2); }
        __syncthreads();
#pragma unroll
        for (int dd = 0; dd < 8; ++dd) {
            float4 q4 = *(const float4*)(qsT + (dc + dd) * 36 + rg * 4);
            float4 kv = *(const float4*)(KVs + dd * 132 + e4);
            float qa4[4] = {q4.x, q4.y, q4.z, q4.w};
            float kb[4]  = {kv.x, kv.y, kv.z, kv.w};
#pragma unroll
            for (int i = 0; i < 4; ++i)
#pragma unroll
                for (int j = 0; j < 4; ++j)
                    acc2[i][j] = fmaf(qa4[i], kb[j], acc2[i][j]);
        }
    }
#pragma unroll
    for (int i = 0; i < 4; ++i) {
        int r = rg * 4 + i; float z = zden[r];
        uint2 xr = *(const uint2*)(Xg + (m0 + r) * DM + e4);
        zs[r * 132 + e4 + 0] = fmaf(acc2[i][0], z, lo16(xr.x));
        zs[r * 132 + e4 + 1] = fmaf(acc2[i][1], z, hi16(xr.x));
        zs[r * 132 + e4 + 2] = fmaf(acc2[i][2], z, lo16(xr.y));
        zs[r * 132 + e4 + 3] = fmaf(acc2[i][3], z, hi16(xr.y));
    }
    __syncthreads();
    int wv = t >> 6, ln = t & 63;
    float g0 = b2f(g[ln]), g1v = b2f(g[64 + ln]);
    float be0 = b2f(beta[ln]), be1 = b2f(beta[64 + ln]);
#pragma unroll
    for (int q = 0; q < 8; ++q) {
        int r = wv * 8 + q;
        float v0 = zs[r * 132 + ln], v1 = zs[r * 132 + 64 + ln];
        float sum = v0 + v1, sq = v0 * v0 + v1 * v1;
#pragma unroll
        for (int off = 32; off > 0; off >>= 1) {
            sum += __shfl_xor(sum, off, 64);
            sq  += __shfl_xor(sq,  off, 64);
        }
        float mean = sum * 0.0078125f;
        float var  = sq * 0.0078125f - mean * mean;
        float rstd = rsqrtf(fmaxf(var, 0.f) + 1e-5f);
        Xout[(m0 + r) * DM + ln]      = f2b((v0 - mean) * rstd * g0  + be0);
        Xout[(m0 + r) * DM + 64 + ln] = f2b((v1 - mean) * rstd * g1v + be1);
    }
}

// ================= fused MLP via MFMA =================
// relu(X W1^T + b1) W2^T + b2 + X → LN, block = 128 rows, 4 waves.
// Wave w owns rows w*32..w*32+31 for FF1 and FF2 (H never crosses waves).
// MFMA 16x16x32 bf16: A-frag lane(L): A[m=L&15][k=(L>>4)*8+j]; C/D: col=L&15,
// row=(L>>4)*4+reg (verified layouts per guide §3).
__global__ __launch_bounds__(256) void mlp_kernel(
    const u16* X, const u16* __restrict__ W1, const u16* __restrict__ b1,
    const u16* __restrict__ W2, const u16* __restrict__ b2,
    u16* Xout, const u16* __restrict__ g, const u16* __restrict__ beta)
{
    __shared__ __align__(16) char sm_[65536];
    u16* As  = (u16*)sm_;             // 32KB [r][k] 16-slot xor(r&15)
    u16* W1c = (u16*)(sm_ + 32768);   // 16KB [c][k] 16-slot xor(c&15)
    u16* Hc  = W1c;                   // 16KB [m][f0..63] 8-slot xor(m&7) (aliases W1c)
    u16* W2c = (u16*)(sm_ + 49152);   // 16KB [d][f0..63] 8-slot xor(d&7)
    float* zs = (float*)sm_;          // 64KB epilogue overlay
    const int t = threadIdx.x;
    const int m0 = blockIdx.x * 128;
    const int w  = t >> 6;            // wave 0..3
    const int lq = (t >> 4) & 3;      // quad within wave
    const int lr = t & 15;

    // stage X tile (128x128 bf16)
#pragma unroll
    for (int i = 0; i < 8; ++i) {
        int e = (i * 256 + t) * 8; int r = e >> 7, k0 = e & 127, sl = k0 >> 3;
        *(uint4*)(As + r * 128 + (((sl ^ (r & 15)) & 15) << 3)) =
            *(const uint4*)(X + (size_t)(m0 + r) * DM + k0);
    }

    const f32x4 zero4 = {0.f, 0.f, 0.f, 0.f};
    f32x4 zacc[2][8];
#pragma unroll
    for (int mt = 0; mt < 2; ++mt)
#pragma unroll
        for (int ct = 0; ct < 8; ++ct) zacc[mt][ct] = zero4;

    for (int fc = 0; fc < DFF; fc += 64) {
        __syncthreads();   // prev FF2 reads of Hc(=W1c)/W2c done; As visible (1st iter)
#pragma unroll
        for (int i = 0; i < 4; ++i) {
            int e = (i * 256 + t) * 8; int c = e >> 7, k0 = e & 127, sl = k0 >> 3;
            *(uint4*)(W1c + c * 128 + (((sl ^ (c & 15)) & 15) << 3)) =
                *(const uint4*)(W1 + (size_t)(fc + c) * DM + k0);
        }
#pragma unroll
        for (int i = 0; i < 4; ++i) {
            int e = (i * 256 + t) * 8; int d = e >> 6, f0 = e & 63, sl = f0 >> 3;
            *(uint4*)(W2c + d * 64 + (((sl ^ (d & 7)) & 7) << 3)) =
                *(const uint4*)(W2 + (size_t)d * DFF + fc + f0);
        }
        __syncthreads();
        // ---- FF1: H[128x64] = relu(A[128x128] · W1c^T + b1) ----
        f32x4 hacc[2][4];
#pragma unroll
        for (int mt = 0; mt < 2; ++mt)
#pragma unroll
            for (int ct = 0; ct < 4; ++ct) hacc[mt][ct] = zero4;
#pragma unroll
        for (int kc = 0; kc < 4; ++kc) {
            bf16x8 af[2];
#pragma unroll
            for (int mt = 0; mt < 2; ++mt) {
                int r = w * 32 + mt * 16 + lr;   // r & 15 == lr
                af[mt] = *(const bf16x8*)(As + r * 128 + ((((kc * 4 + lq) ^ lr) & 15) << 3));
            }
#pragma unroll
            for (int ct = 0; ct < 4; ++ct) {
                int c = ct * 16 + lr;            // c & 15 == lr
                bf16x8 bf_ = *(const bf16x8*)(W1c + c * 128 + ((((kc * 4 + lq) ^ lr) & 15) << 3));
                hacc[0][ct] = __builtin_amdgcn_mfma_f32_16x16x32_bf16(af[0], bf_, hacc[0][ct], 0, 0, 0);
                hacc[1][ct] = __builtin_amdgcn_mfma_f32_16x16x32_bf16(af[1], bf_, hacc[1][ct], 0, 0, 0);
            }
        }
        __syncthreads();   // all waves' FF1 reads of W1c done before H overwrite
        // bias + relu, C-layout → A-layout bf16 store (wave-local rows)
#pragma unroll
        for (int ct = 0; ct < 4; ++ct) {
            int f = ct * 16 + lr;
            float hbv = b2f(b1[fc + f]);
#pragma unroll
            for (int mt = 0; mt < 2; ++mt)
#pragma unroll
                for (int j = 0; j < 4; ++j) {
                    int m = w * 32 + mt * 16 + lq * 4 + j;
                    float v = fmaxf(hacc[mt][ct][j] + hbv, 0.f);
                    Hc[m * 64 + ((((f >> 3) ^ (m & 7)) & 7) << 3) + (f & 7)] = f2b(v);
                }
        }
        __syncthreads();   // conservative (H rows are wave-local, but cheap insurance)
        // ---- FF2: zacc += H[128x64] · W2c^T ----
#pragma unroll
        for (int kc = 0; kc < 2; ++kc) {
            bf16x8 ha[2];
#pragma unroll
            for (int mt = 0; mt < 2; ++mt) {
                int m = w * 32 + mt * 16 + lr;   // m & 7 == lr & 7
                ha[mt] = *(const bf16x8*)(Hc + m * 64 + ((((kc * 4 + lq) ^ (lr & 7)) & 7) << 3));
            }
#pragma unroll
            for (int ct = 0; ct < 8; ++ct) {
                int d = ct * 16 + lr;            // d & 7 == lr & 7
                bf16x8 wb = *(const bf16x8*)(W2c + d * 64 + ((((kc * 4 + lq) ^ (lr & 7)) & 7) << 3));
                zacc[0][ct] = __builtin_amdgcn_mfma_f32_16x16x32_bf16(ha[0], wb, zacc[0][ct], 0, 0, 0);
                zacc[1][ct] = __builtin_amdgcn_mfma_f32_16x16x32_bf16(ha[1], wb, zacc[1][ct], 0, 0, 0);
            }
        }
    }
    __syncthreads();   // last FF2 reads done; zs overlays all of LDS
    // z = zacc + b2 → zs (C-layout scatter)
#pragma unroll
    for (int ct = 0; ct < 8; ++ct) {
        float bbv = b2f(b2[ct * 16 + lr]);
#pragma unroll
        for (int mt = 0; mt < 2; ++mt)
#pragma unroll
            for (int j = 0; j < 4; ++j) {
                int r = w * 32 + mt * 16 + lq * 4 + j;
                zs[r * 128 + ct * 16 + lr] = zacc[mt][ct][j] + bbv;
            }
    }
    __syncthreads();
    // LN with residual folded into the read (X re-read hits L1)
    int wv = t >> 6, ln = t & 63;
    float g0 = b2f(g[ln]), g1v = b2f(g[64 + ln]);
    float be0 = b2f(beta[ln]), be1 = b2f(beta[64 + ln]);
    for (int q = 0; q < 32; ++q) {
        int r = wv * 32 + q;
        float v0 = zs[r * 128 + ln]      + b2f(X[(size_t)(m0 + r) * DM + ln]);
        float v1 = zs[r * 128 + 64 + ln] + b2f(X[(size_t)(m0 + r) * DM + 64 + ln]);
        float sum = v0 + v1, sq = v0 * v0 + v1 * v1;
#pragma unroll
        for (int off = 32; off > 0; off >>= 1) {
            sum += __shfl_xor(sum, off, 64);
            sq  += __shfl_xor(sq,  off, 64);
        }
        float mean = sum * 0.0078125f;
        float var  = sq * 0.0078125f - mean * mean;
        float rstd = rsqrtf(fmaxf(var, 0.f) + 1e-5f);
        Xout[(size_t)(m0 + r) * DM + ln]      = f2b((v0 - mean) * rstd * g0  + be0);
        Xout[(size_t)(m0 + r) * DM + 64 + ln] = f2b((v1 - mean) * rstd * g1v + be1);
    }
}

// ================= mean over S + final FC (flag-dependent output dtype) ========
__global__ __launch_bounds__(128) void pool_fc_kernel(
    const u16* __restrict__ X, const u16* __restrict__ fcw,
    const u16* __restrict__ fcb, void* __restrict__ Out,
    const int* __restrict__ flag)
{
    __shared__ float pool[128];
    const int b = blockIdx.x, t = threadIdx.x;
    float acc = 0.f;
    for (int s = 0; s < S_LEN; ++s)
        acc += b2f(X[((size_t)s * B_SZ + b) * DM + t]);
    pool[t] = acc * (1.0f / 256.0f);
    __syncthreads();
    if (t < 10) {
        float o = b2f(fcb[t]);
        for (int d = 0; d < 128; ++d) o += pool[d] * b2f(fcw[t * 128 + d]);
        if (*flag) ((float*)Out)[b * 10 + t] = o;
        else       ((u16*)Out)[b * 10 + t] = f2b(o);
    }
}

// ================= launch =================
extern "C" void kernel_launch(void* const* d_in, const int* in_sizes, int n_in,
                              void* d_out, int out_size, void* d_ws, size_t ws_size,
                              hipStream_t stream)
{
    const int* src = (const int*)d_in[0];

    char* ws = (char*)d_ws;
    u16*   X    = (u16*)ws;
    float* KV   = (float*)(ws + 33554432);
    float* Ksum = (float*)(ws + 50331648);
    int*   flag = (int*)(ws + 50462720);
    u16*   cn   = (u16*)(ws + 50462976);

    // canonical bf16 offsets (elements)
    u16* emb = cn + 0;
    u16* wq  = cn + 16384;
    u16* bq  = cn + 49152;
    u16* wk  = cn + 49408;
    u16* bk  = cn + 82176;
    u16* wv  = cn + 82432;
    u16* bvp = cn + 115200;
    u16* w1  = cn + 115456;
    u16* b1  = cn + 246528;
    u16* w2  = cn + 247552;
    u16* b2  = cn + 378624;
    u16* g1  = cn + 378880;
    u16* be1 = cn + 379136;
    u16* g2  = cn + 379392;
    u16* be2 = cn + 379648;
    u16* fcw = cn + 379904;
    u16* fcb = cn + 381184;

    detect_kernel<<<1, 256, 0, stream>>>((const u32*)d_in[1], flag);

    Ptrs ps;
    for (int i = 0; i < 17; ++i) ps.p[i] = d_in[i + 1];
    convert_kernel<<<195, 256, 0, stream>>>(ps, cn, flag);

    embed_kernel<<<MROWS * 64 / 256, 256, 0, stream>>>(src, emb, X);

    for (int l = 0; l < 2; ++l) {
        kvproj_kernel<<<S_LEN * 2, 256, 0, stream>>>(
            X, wk + l * DM * DM, bk + l * DM, wv + l * DM * DM, bvp + l * DM, KV, Ksum);
        attn_ln_kernel<<<S_LEN * 16, 256, 0, stream>>>(
            X, wq + l * DM * DM, bq + l * DM, KV, Ksum, X, g1 + l * DM, be1 + l * DM);
        mlp_kernel<<<MROWS / 128, 256, 0, stream>>>(
            X, w1 + l * DFF * DM, b1 + l * DFF, w2 + l * DM * DFF, b2 + l * DM,
            X, g2 + l * DM, be2 + l * DM);
    }

    pool_fc_kernel<<<B_SZ, 128, 0, stream>>>(X, fcw, fcb, d_out, flag);
}

// Round 5
// 448.246 us; speedup vs baseline: 6.6407x; 3.6425x over previous
//
#include <hip/hip_runtime.h>

typedef unsigned short u16;
typedef unsigned int u32;
typedef short bf16x8 __attribute__((ext_vector_type(8)));
typedef float f32x4 __attribute__((ext_vector_type(4)));

// ---------- bf16 helpers ----------
__device__ __forceinline__ float b2f(u16 v) { return __uint_as_float(((u32)v) << 16); }
__device__ __forceinline__ u16 f2b(float f) {   // round-to-nearest-even
    u32 x = __float_as_uint(f);
    return (u16)((x + 0x7fffu + ((x >> 16) & 1u)) >> 16);
}
__device__ __forceinline__ float lo16(u32 w) { return __uint_as_float(w << 16); }
__device__ __forceinline__ float hi16(u32 w) { return __uint_as_float(w & 0xffff0000u); }

#define S_LEN 256
#define B_SZ  512
#define DM    128
#define DFF   512
#define MROWS (S_LEN * B_SZ)   // 131072

// swizzled LDS address for a [row][128] bf16 tile, 16 slots of 8
__device__ __forceinline__ int sw16(int r, int d) {
    return r * 128 + ((((d >> 3) ^ (r & 15)) & 15) << 3) + (d & 7);
}

// ================= dtype detect =================
__global__ __launch_bounds__(256) void detect_kernel(const u32* __restrict__ embw,
                                                     int* __restrict__ flag) {
    int z = 0, big = 0;
    for (int i = threadIdx.x; i < 8192; i += 256) {
        u32 w = embw[i];
        u32 lo = w & 0xffffu;
        if (lo == 0u) z++;
        else if (((lo >> 7) & 0xffu) >= 0xC0u) big++;
    }
#pragma unroll
    for (int off = 32; off > 0; off >>= 1) {
        z   += __shfl_xor(z, off, 64);
        big += __shfl_xor(big, off, 64);
    }
    __shared__ int zz[4], bb[4];
    if ((threadIdx.x & 63) == 0) { zz[threadIdx.x >> 6] = z; bb[threadIdx.x >> 6] = big; }
    __syncthreads();
    if (threadIdx.x == 0) {
        int Z = zz[0] + zz[1] + zz[2] + zz[3];
        int Bc = bb[0] + bb[1] + bb[2] + bb[3];
        flag[0] = (Z > 4096 || Bc > 16) ? 1 : 0;   // 1 = fp32 storage
    }
}

// ================= convert all float inputs -> canonical bf16 =================
struct Ptrs { const void* p[17]; };

__global__ __launch_bounds__(256) void convert_kernel(Ptrs ps, u16* __restrict__ canon,
                                                      const int* __restrict__ flag) {
    const int cnt[17] = {16384,32768,256,32768,256,32768,256,131072,1024,131072,
                         256,256,256,256,256,1280,10};
    const int off[17] = {0,16384,49152,49408,82176,82432,115200,115456,246528,
                         247552,378624,378880,379136,379392,379648,379904,381184};
    const int bst[18] = {0,8,24,25,41,42,58,59,123,124,188,189,190,191,192,193,194,195};
    const int isf = *flag;
    const int blk = blockIdx.x;
    int idx = 0;
#pragma unroll
    for (int i = 0; i < 17; ++i) if (blk >= bst[i + 1]) idx = i + 1;
    const int local = blk - bst[idx];
    const int n = cnt[idx];
    const void* sp = ps.p[idx];
    u16* dp = canon + off[idx];
#pragma unroll
    for (int j = 0; j < 8; ++j) {
        int e = local * 2048 + j * 256 + threadIdx.x;
        if (e < n) {
            u16 v = isf ? f2b(((const float*)sp)[e]) : ((const u16*)sp)[e];
            dp[e] = v;
        }
    }
}

// ================= embed + positional encoding → X bf16 =================
__global__ __launch_bounds__(256) void embed_kernel(const int* __restrict__ src,
                                                    const u16* __restrict__ emb,
                                                    u16* __restrict__ X) {
    int idx = blockIdx.x * 256 + threadIdx.x;      // one per bf16 pair
    int d2 = idx & 63;
    int m = idx >> 6;              // s*512 + b
    int s = m >> 9;
    int b = m & 511;
    int tok = src[b * S_LEN + s];
    int d = d2 * 2;
    float e0 = b2f(emb[tok * DM + d])     * 11.3137084989847604f; // sqrt(128)
    float e1 = b2f(emb[tok * DM + d + 1]) * 11.3137084989847604f;
    float ang = (float)s * expf((float)d * -0.0719557841560639f); // -ln(10000)/128
    float v0 = e0 + sinf(ang);
    float v1 = e1 + cosf(ang);
    u32 w = (u32)f2b(v0) | ((u32)f2b(v1) << 16);
    *(u32*)(X + (size_t)m * DM + d) = w;
}

// ================= kvproj (MFMA): per-s K/V proj + KV^T + Ksum =================
// block = s, 4 waves. Weights VGPR-resident as B-frags. Outputs:
//   KVt global bf16 [s][e][d] (pre-transposed for attn B-frags), Ksum fp32.
__global__ __launch_bounds__(256) void kvproj_kernel(
    const u16* __restrict__ X, const u16* __restrict__ Wk, const u16* __restrict__ bk,
    const u16* __restrict__ Wv, const u16* __restrict__ bv,
    u16* __restrict__ KVt, float* __restrict__ Ksum)
{
    __shared__ __align__(16) char sm_[49152];
    u16* Xs = (u16*)sm_;             // 16KB: 64 rows x 128 k, sw16
    u16* Kt = (u16*)(sm_ + 16384);   // 16KB: 128 d x 64 b, 8-slot swizzle
    u16* Vt = (u16*)(sm_ + 32768);   // 16KB: 128 e x 64 b
    const int s = blockIdx.x, t = threadIdx.x;
    const int w = t >> 6, quad = (t >> 4) & 3, lr = t & 15;
    const u16* Xg = X + (size_t)s * B_SZ * DM;

    // VGPR weight B-frags: e = w*32 + ct*16 + lr, k = kc*32 + quad*8
    bf16x8 wkf[2][4], wvf[2][4];
    float kb[2], vb[2];
#pragma unroll
    for (int ct = 0; ct < 2; ++ct) {
        int e = w * 32 + ct * 16 + lr;
#pragma unroll
        for (int kc = 0; kc < 4; ++kc) {
            wkf[ct][kc] = *(const bf16x8*)(Wk + e * 128 + kc * 32 + quad * 8);
            wvf[ct][kc] = *(const bf16x8*)(Wv + e * 128 + kc * 32 + quad * 8);
        }
        kb[ct] = b2f(bk[e]);
        vb[ct] = b2f(bv[e]);
    }

    const f32x4 z4 = {0.f, 0.f, 0.f, 0.f};
    f32x4 kvacc[2][8];
#pragma unroll
    for (int dt = 0; dt < 2; ++dt)
#pragma unroll
        for (int ct = 0; ct < 8; ++ct) kvacc[dt][ct] = z4;
    float ks[2] = {0.f, 0.f};

    for (int b0 = 0; b0 < B_SZ; b0 += 64) {
        __syncthreads();   // prev KV reads of Kt/Vt and Xs reads done
#pragma unroll
        for (int i = 0; i < 4; ++i) {
            int e8 = (i * 256 + t) * 8; int r = e8 >> 7, k0 = e8 & 127;
            *(uint4*)(Xs + sw16(r, k0)) = *(const uint4*)(Xg + (size_t)(b0 + r) * DM + k0);
        }
        __syncthreads();
        // ---- K projection: rows = chunk 64, cols = wave e-slice 32 ----
        f32x4 pa[4][2];
#pragma unroll
        for (int mt = 0; mt < 4; ++mt) { pa[mt][0] = z4; pa[mt][1] = z4; }
#pragma unroll
        for (int kc = 0; kc < 4; ++kc) {
            bf16x8 a[4];
#pragma unroll
            for (int mt = 0; mt < 4; ++mt)
                a[mt] = *(const bf16x8*)(Xs + sw16(mt * 16 + lr, kc * 32 + quad * 8));
#pragma unroll
            for (int ct = 0; ct < 2; ++ct)
#pragma unroll
                for (int mt = 0; mt < 4; ++mt)
                    pa[mt][ct] = __builtin_amdgcn_mfma_f32_16x16x32_bf16(a[mt], wkf[ct][kc], pa[mt][ct], 0, 0, 0);
        }
#pragma unroll
        for (int ct = 0; ct < 2; ++ct) {
            int e = w * 32 + ct * 16 + lr, e7 = e & 7;
#pragma unroll
            for (int mt = 0; mt < 4; ++mt) {
                u16 h[4]; float ssum = 0.f;
#pragma unroll
                for (int j = 0; j < 4; ++j) {
                    float v = fmaxf(pa[mt][ct][j] + kb[ct], 0.f) + 1e-6f;
                    h[j] = f2b(v); ssum += b2f(h[j]);
                }
                ks[ct] += ssum;
                uint2 pk; pk.x = (u32)h[0] | ((u32)h[1] << 16); pk.y = (u32)h[2] | ((u32)h[3] << 16);
                int bs = mt * 2 + (quad >> 1);          // b>>3
                *(uint2*)(Kt + e * 64 + (((bs ^ e7) & 7) << 3) + (quad & 1) * 4) = pk;
            }
        }
        // ---- V projection ----
#pragma unroll
        for (int mt = 0; mt < 4; ++mt) { pa[mt][0] = z4; pa[mt][1] = z4; }
#pragma unroll
        for (int kc = 0; kc < 4; ++kc) {
            bf16x8 a[4];
#pragma unroll
            for (int mt = 0; mt < 4; ++mt)
                a[mt] = *(const bf16x8*)(Xs + sw16(mt * 16 + lr, kc * 32 + quad * 8));
#pragma unroll
            for (int ct = 0; ct < 2; ++ct)
#pragma unroll
                for (int mt = 0; mt < 4; ++mt)
                    pa[mt][ct] = __builtin_amdgcn_mfma_f32_16x16x32_bf16(a[mt], wvf[ct][kc], pa[mt][ct], 0, 0, 0);
        }
#pragma unroll
        for (int ct = 0; ct < 2; ++ct) {
            int e = w * 32 + ct * 16 + lr, e7 = e & 7;
#pragma unroll
            for (int mt = 0; mt < 4; ++mt) {
                u16 h[4];
#pragma unroll
                for (int j = 0; j < 4; ++j) h[j] = f2b(pa[mt][ct][j] + vb[ct]);
                uint2 pk; pk.x = (u32)h[0] | ((u32)h[1] << 16); pk.y = (u32)h[2] | ((u32)h[3] << 16);
                int bs = mt * 2 + (quad >> 1);
                *(uint2*)(Vt + e * 64 + (((bs ^ e7) & 7) << 3) + (quad & 1) * 4) = pk;
            }
        }
        __syncthreads();
        // ---- KV += K^T · V  (contraction over chunk b) ----
#pragma unroll
        for (int kc = 0; kc < 2; ++kc) {
            bf16x8 ka[2];
#pragma unroll
            for (int dt = 0; dt < 2; ++dt) {
                int d = (2 * w + dt) * 16 + lr;
                ka[dt] = *(const bf16x8*)(Kt + d * 64 + ((((kc * 4 + quad) ^ (d & 7)) & 7) << 3));
            }
#pragma unroll
            for (int ct = 0; ct < 8; ++ct) {
                int e = ct * 16 + lr;
                bf16x8 vf = *(const bf16x8*)(Vt + e * 64 + ((((kc * 4 + quad) ^ (e & 7)) & 7) << 3));
                kvacc[0][ct] = __builtin_amdgcn_mfma_f32_16x16x32_bf16(ka[0], vf, kvacc[0][ct], 0, 0, 0);
                kvacc[1][ct] = __builtin_amdgcn_mfma_f32_16x16x32_bf16(ka[1], vf, kvacc[1][ct], 0, 0, 0);
            }
        }
    }
    // Ksum: reduce over quad (lanes xor 16, 32), quad 0 writes
#pragma unroll
    for (int ct = 0; ct < 2; ++ct) {
        float v = ks[ct];
        v += __shfl_xor(v, 16, 64);
        v += __shfl_xor(v, 32, 64);
        if (quad == 0) Ksum[s * 128 + w * 32 + ct * 16 + lr] = v;
    }
    // KVt global bf16 [e][d]: consecutive C-regs j = consecutive d → uint2 packs
    u16* KVg = KVt + (size_t)s * (DM * DM);
#pragma unroll
    for (int dt = 0; dt < 2; ++dt) {
        int d0 = (2 * w + dt) * 16 + quad * 4;
#pragma unroll
        for (int ct = 0; ct < 8; ++ct) {
            int e = ct * 16 + lr;
            u16 h[4];
#pragma unroll
            for (int j = 0; j < 4; ++j) h[j] = f2b(kvacc[dt][ct][j]);
            uint2 pk; pk.x = (u32)h[0] | ((u32)h[1] << 16); pk.y = (u32)h[2] | ((u32)h[3] << 16);
            *(uint2*)(KVg + e * 128 + d0) = pk;
        }
    }
}

// ================= attn (MFMA): Q-proj + Q·KV·Z + residual + LN =================
// block = (s, 128-row chunk). X/Xout alias (in-place, block-disjoint rows).
__global__ __launch_bounds__(256) void attn_ln_kernel(
    const u16* X, const u16* __restrict__ Wq, const u16* __restrict__ bq,
    const u16* __restrict__ KVt, const float* __restrict__ Ksum,
    u16* Xout, const u16* __restrict__ g, const u16* __restrict__ beta)
{
    __shared__ __align__(16) char sm_[65536];
    u16* R1 = (u16*)sm_;            // Wq staged → Qs (A-frag layout)
    u16* R2 = (u16*)(sm_ + 32768);  // Xc staged → KVt staged
    const int blk = blockIdx.x, s = blk >> 2, rc = blk & 3, t = threadIdx.x;
    const int w = t >> 6, quad = (t >> 4) & 3, lr = t & 15;
    const size_t m0 = (size_t)s * B_SZ + rc * 128;

#pragma unroll
    for (int i = 0; i < 8; ++i) {
        int e8 = (i * 256 + t) * 8; int r = e8 >> 7, k0 = e8 & 127;
        *(uint4*)(R1 + sw16(r, k0)) = *(const uint4*)(Wq + e8);
        *(uint4*)(R2 + sw16(r, k0)) = *(const uint4*)(X + (m0 + r) * DM + k0);
    }
    __syncthreads();
    // ---- Q projection: wave rows w*32 .. +31 ----
    const f32x4 z4 = {0.f, 0.f, 0.f, 0.f};
    f32x4 qacc[2][8];
#pragma unroll
    for (int mt = 0; mt < 2; ++mt)
#pragma unroll
        for (int ct = 0; ct < 8; ++ct) qacc[mt][ct] = z4;
#pragma unroll
    for (int kc = 0; kc < 4; ++kc) {
        bf16x8 a[2];
#pragma unroll
        for (int mt = 0; mt < 2; ++mt)
            a[mt] = *(const bf16x8*)(R2 + sw16(w * 32 + mt * 16 + lr, kc * 32 + quad * 8));
#pragma unroll
        for (int ct = 0; ct < 8; ++ct) {
            bf16x8 wf = *(const bf16x8*)(R1 + sw16(ct * 16 + lr, kc * 32 + quad * 8));
            qacc[0][ct] = __builtin_amdgcn_mfma_f32_16x16x32_bf16(a[0], wf, qacc[0][ct], 0, 0, 0);
            qacc[1][ct] = __builtin_amdgcn_mfma_f32_16x16x32_bf16(a[1], wf, qacc[1][ct], 0, 0, 0);
        }
    }
    __syncthreads();   // Wq/Xc reads complete; regions may be overwritten
    // ---- epilogue: relu+eps, Z partials (rounded Q), transpose-store Qs ----
    float ksm[8], bqv[8];
#pragma unroll
    for (int ct = 0; ct < 8; ++ct) {
        ksm[ct] = Ksum[s * 128 + ct * 16 + lr];
        bqv[ct] = b2f(bq[ct * 16 + lr]);
    }
    float zden[2][4];
#pragma unroll
    for (int mt = 0; mt < 2; ++mt)
#pragma unroll
        for (int j = 0; j < 4; ++j) zden[mt][j] = 0.f;
#pragma unroll
    for (int mt = 0; mt < 2; ++mt)
#pragma unroll
        for (int ct = 0; ct < 8; ++ct) {
            int d = ct * 16 + lr;
#pragma unroll
            for (int j = 0; j < 4; ++j) {
                float qv = fmaxf(qacc[mt][ct][j] + bqv[ct], 0.f) + 1e-6f;
                u16 qb16 = f2b(qv);
                zden[mt][j] += b2f(qb16) * ksm[ct];
                int b = w * 32 + mt * 16 + quad * 4 + j;
                R1[sw16(b, d)] = qb16;     // Qs
            }
        }
#pragma unroll
    for (int mt = 0; mt < 2; ++mt)
#pragma unroll
        for (int j = 0; j < 4; ++j) {
            float v = zden[mt][j];
            v += __shfl_xor(v, 1, 64); v += __shfl_xor(v, 2, 64);
            v += __shfl_xor(v, 4, 64); v += __shfl_xor(v, 8, 64);
            zden[mt][j] = 1.f / (v + 1e-6f);
        }
    // ---- stage KVt (bf16 [e][d]) over dead Xc ----
    const u16* KVg = KVt + (size_t)s * (DM * DM);
#pragma unroll
    for (int i = 0; i < 8; ++i) {
        int e8 = (i * 256 + t) * 8; int r = e8 >> 7, k0 = e8 & 127;
        *(uint4*)(R2 + sw16(r, k0)) = *(const uint4*)(KVg + e8);
    }
    __syncthreads();
    // ---- O = Q · KV ----
    f32x4 oacc[2][8];
#pragma unroll
    for (int mt = 0; mt < 2; ++mt)
#pragma unroll
        for (int ct = 0; ct < 8; ++ct) oacc[mt][ct] = z4;
#pragma unroll
    for (int kc = 0; kc < 4; ++kc) {
        bf16x8 qa[2];
#pragma unroll
        for (int mt = 0; mt < 2; ++mt)
            qa[mt] = *(const bf16x8*)(R1 + sw16(w * 32 + mt * 16 + lr, kc * 32 + quad * 8));
#pragma unroll
        for (int ct = 0; ct < 8; ++ct) {
            bf16x8 kf = *(const bf16x8*)(R2 + sw16(ct * 16 + lr, kc * 32 + quad * 8));
            oacc[0][ct] = __builtin_amdgcn_mfma_f32_16x16x32_bf16(qa[0], kf, oacc[0][ct], 0, 0, 0);
            oacc[1][ct] = __builtin_amdgcn_mfma_f32_16x16x32_bf16(qa[1], kf, oacc[1][ct], 0, 0, 0);
        }
    }
    // ---- epilogue: *Z + residual + register-only LN ----
    float gv[8], bev[8];
#pragma unroll
    for (int ct = 0; ct < 8; ++ct) {
        gv[ct]  = b2f(g[ct * 16 + lr]);
        bev[ct] = b2f(beta[ct * 16 + lr]);
    }
#pragma unroll
    for (int mt = 0; mt < 2; ++mt)
#pragma unroll
        for (int j = 0; j < 4; ++j) {
            int b = w * 32 + mt * 16 + quad * 4 + j;
            const u16* xr = X + (m0 + b) * DM;
            float vals[8], sum = 0.f, sq = 0.f;
#pragma unroll
            for (int ct = 0; ct < 8; ++ct) {
                float v = fmaf(oacc[mt][ct][j], zden[mt][j], b2f(xr[ct * 16 + lr]));
                vals[ct] = v; sum += v; sq += v * v;
            }
            sum += __shfl_xor(sum, 1, 64); sq += __shfl_xor(sq, 1, 64);
            sum += __shfl_xor(sum, 2, 64); sq += __shfl_xor(sq, 2, 64);
            sum += __shfl_xor(sum, 4, 64); sq += __shfl_xor(sq, 4, 64);
            sum += __shfl_xor(sum, 8, 64); sq += __shfl_xor(sq, 8, 64);
            float mean = sum * 0.0078125f;
            float var  = sq * 0.0078125f - mean * mean;
            float rstd = rsqrtf(fmaxf(var, 0.f) + 1e-5f);
            u16* xo = Xout + (m0 + b) * DM;
#pragma unroll
            for (int ct = 0; ct < 8; ++ct)
                xo[ct * 16 + lr] = f2b((vals[ct] - mean) * rstd * gv[ct] + bev[ct]);
        }
}

// ================= fused MLP via MFMA (unchanged from r4) =================
__global__ __launch_bounds__(256) void mlp_kernel(
    const u16* X, const u16* __restrict__ W1, const u16* __restrict__ b1,
    const u16* __restrict__ W2, const u16* __restrict__ b2,
    u16* Xout, const u16* __restrict__ g, const u16* __restrict__ beta)
{
    __shared__ __align__(16) char sm_[65536];
    u16* As  = (u16*)sm_;             // 32KB [r][k] sw16
    u16* W1c = (u16*)(sm_ + 32768);   // 16KB [c][k] sw16
    u16* Hc  = W1c;                   // 16KB [m][f] 8-slot (aliases W1c)
    u16* W2c = (u16*)(sm_ + 49152);   // 16KB [d][f] 8-slot
    float* zs = (float*)sm_;          // epilogue overlay
    const int t = threadIdx.x;
    const int m0 = blockIdx.x * 128;
    const int w  = t >> 6;
    const int lq = (t >> 4) & 3;
    const int lr = t & 15;

#pragma unroll
    for (int i = 0; i < 8; ++i) {
        int e = (i * 256 + t) * 8; int r = e >> 7, k0 = e & 127;
        *(uint4*)(As + sw16(r, k0)) = *(const uint4*)(X + (size_t)(m0 + r) * DM + k0);
    }

    const f32x4 zero4 = {0.f, 0.f, 0.f, 0.f};
    f32x4 zacc[2][8];
#pragma unroll
    for (int mt = 0; mt < 2; ++mt)
#pragma unroll
        for (int ct = 0; ct < 8; ++ct) zacc[mt][ct] = zero4;

    for (int fc = 0; fc < DFF; fc += 64) {
        __syncthreads();
#pragma unroll
        for (int i = 0; i < 4; ++i) {
            int e = (i * 256 + t) * 8; int c = e >> 7, k0 = e & 127;
            *(uint4*)(W1c + sw16(c, k0)) = *(const uint4*)(W1 + (size_t)(fc + c) * DM + k0);
        }
#pragma unroll
        for (int i = 0; i < 4; ++i) {
            int e = (i * 256 + t) * 8; int d = e >> 6, f0 = e & 63, sl = f0 >> 3;
            *(uint4*)(W2c + d * 64 + (((sl ^ (d & 7)) & 7) << 3)) =
                *(const uint4*)(W2 + (size_t)d * DFF + fc + f0);
        }
        __syncthreads();
        f32x4 hacc[2][4];
#pragma unroll
        for (int mt = 0; mt < 2; ++mt)
#pragma unroll
            for (int ct = 0; ct < 4; ++ct) hacc[mt][ct] = zero4;
#pragma unroll
        for (int kc = 0; kc < 4; ++kc) {
            bf16x8 af[2];
#pragma unroll
            for (int mt = 0; mt < 2; ++mt)
                af[mt] = *(const bf16x8*)(As + sw16(w * 32 + mt * 16 + lr, kc * 32 + lq * 8));
#pragma unroll
            for (int ct = 0; ct < 4; ++ct) {
                bf16x8 bf_ = *(const bf16x8*)(W1c + sw16(ct * 16 + lr, kc * 32 + lq * 8));
                hacc[0][ct] = __builtin_amdgcn_mfma_f32_16x16x32_bf16(af[0], bf_, hacc[0][ct], 0, 0, 0);
                hacc[1][ct] = __builtin_amdgcn_mfma_f32_16x16x32_bf16(af[1], bf_, hacc[1][ct], 0, 0, 0);
            }
        }
        __syncthreads();
#pragma unroll
        for (int ct = 0; ct < 4; ++ct) {
            int f = ct * 16 + lr;
            float hbv = b2f(b1[fc + f]);
#pragma unroll
            for (int mt = 0; mt < 2; ++mt)
#pragma unroll
                for (int j = 0; j < 4; ++j) {
                    int m = w * 32 + mt * 16 + lq * 4 + j;
                    float v = fmaxf(hacc[mt][ct][j] + hbv, 0.f);
                    Hc[m * 64 + ((((f >> 3) ^ (m & 7)) & 7) << 3) + (f & 7)] = f2b(v);
                }
        }
        __syncthreads();
#pragma unroll
        for (int kc = 0; kc < 2; ++kc) {
            bf16x8 ha[2];
#pragma unroll
            for (int mt = 0; mt < 2; ++mt) {
                int m = w * 32 + mt * 16 + lr;
                ha[mt] = *(const bf16x8*)(Hc + m * 64 + ((((kc * 4 + lq) ^ (lr & 7)) & 7) << 3));
            }
#pragma unroll
            for (int ct = 0; ct < 8; ++ct) {
                int d = ct * 16 + lr;
                bf16x8 wb = *(const bf16x8*)(W2c + d * 64 + ((((kc * 4 + lq) ^ (lr & 7)) & 7) << 3));
                zacc[0][ct] = __builtin_amdgcn_mfma_f32_16x16x32_bf16(ha[0], wb, zacc[0][ct], 0, 0, 0);
                zacc[1][ct] = __builtin_amdgcn_mfma_f32_16x16x32_bf16(ha[1], wb, zacc[1][ct], 0, 0, 0);
            }
        }
    }
    __syncthreads();
#pragma unroll
    for (int ct = 0; ct < 8; ++ct) {
        float bbv = b2f(b2[ct * 16 + lr]);
#pragma unroll
        for (int mt = 0; mt < 2; ++mt)
#pragma unroll
            for (int j = 0; j < 4; ++j) {
                int r = w * 32 + mt * 16 + lq * 4 + j;
                zs[r * 128 + ct * 16 + lr] = zacc[mt][ct][j] + bbv;
            }
    }
    __syncthreads();
    int wv = t >> 6, ln = t & 63;
    float g0 = b2f(g[ln]), g1v = b2f(g[64 + ln]);
    float be0 = b2f(beta[ln]), be1 = b2f(beta[64 + ln]);
    for (int q = 0; q < 32; ++q) {
        int r = wv * 32 + q;
        float v0 = zs[r * 128 + ln]      + b2f(X[(size_t)(m0 + r) * DM + ln]);
        float v1 = zs[r * 128 + 64 + ln] + b2f(X[(size_t)(m0 + r) * DM + 64 + ln]);
        float sum = v0 + v1, sq = v0 * v0 + v1 * v1;
#pragma unroll
        for (int off = 32; off > 0; off >>= 1) {
            sum += __shfl_xor(sum, off, 64);
            sq  += __shfl_xor(sq,  off, 64);
        }
        float mean = sum * 0.0078125f;
        float var  = sq * 0.0078125f - mean * mean;
        float rstd = rsqrtf(fmaxf(var, 0.f) + 1e-5f);
        Xout[(size_t)(m0 + r) * DM + ln]      = f2b((v0 - mean) * rstd * g0  + be0);
        Xout[(size_t)(m0 + r) * DM + 64 + ln] = f2b((v1 - mean) * rstd * g1v + be1);
    }
}

// ================= mean over S + final FC =================
__global__ __launch_bounds__(128) void pool_fc_kernel(
    const u16* __restrict__ X, const u16* __restrict__ fcw,
    const u16* __restrict__ fcb, void* __restrict__ Out,
    const int* __restrict__ flag)
{
    __shared__ float pool[128];
    const int b = blockIdx.x, t = threadIdx.x;
    float acc = 0.f;
    for (int s = 0; s < S_LEN; ++s)
        acc += b2f(X[((size_t)s * B_SZ + b) * DM + t]);
    pool[t] = acc * (1.0f / 256.0f);
    __syncthreads();
    if (t < 10) {
        float o = b2f(fcb[t]);
        for (int d = 0; d < 128; ++d) o += pool[d] * b2f(fcw[t * 128 + d]);
        if (*flag) ((float*)Out)[b * 10 + t] = o;
        else       ((u16*)Out)[b * 10 + t] = f2b(o);
    }
}

// ================= launch =================
extern "C" void kernel_launch(void* const* d_in, const int* in_sizes, int n_in,
                              void* d_out, int out_size, void* d_ws, size_t ws_size,
                              hipStream_t stream)
{
    const int* src = (const int*)d_in[0];

    // ws: X bf16 33.5MB | KVt bf16 8.4MB | Ksum 128KB | flag | canon ~0.76MB
    char* ws = (char*)d_ws;
    u16*   X    = (u16*)ws;
    u16*   KVt  = (u16*)(ws + 33554432);
    float* Ksum = (float*)(ws + 41943040);
    int*   flag = (int*)(ws + 42074112);
    u16*   cn   = (u16*)(ws + 42074368);

    u16* emb = cn + 0;
    u16* wq  = cn + 16384;
    u16* bq  = cn + 49152;
    u16* wk  = cn + 49408;
    u16* bk  = cn + 82176;
    u16* wv  = cn + 82432;
    u16* bvp = cn + 115200;
    u16* w1  = cn + 115456;
    u16* b1  = cn + 246528;
    u16* w2  = cn + 247552;
    u16* b2  = cn + 378624;
    u16* g1  = cn + 378880;
    u16* be1 = cn + 379136;
    u16* g2  = cn + 379392;
    u16* be2 = cn + 379648;
    u16* fcw = cn + 379904;
    u16* fcb = cn + 381184;

    detect_kernel<<<1, 256, 0, stream>>>((const u32*)d_in[1], flag);

    Ptrs ps;
    for (int i = 0; i < 17; ++i) ps.p[i] = d_in[i + 1];
    convert_kernel<<<195, 256, 0, stream>>>(ps, cn, flag);

    embed_kernel<<<MROWS * 64 / 256, 256, 0, stream>>>(src, emb, X);

    for (int l = 0; l < 2; ++l) {
        kvproj_kernel<<<S_LEN, 256, 0, stream>>>(
            X, wk + l * DM * DM, bk + l * DM, wv + l * DM * DM, bvp + l * DM, KVt, Ksum);
        attn_ln_kernel<<<S_LEN * 4, 256, 0, stream>>>(
            X, wq + l * DM * DM, bq + l * DM, KVt, Ksum, X, g1 + l * DM, be1 + l * DM);
        mlp_kernel<<<MROWS / 128, 256, 0, stream>>>(
            X, w1 + l * DFF * DM, b1 + l * DFF, w2 + l * DM * DFF, b2 + l * DM,
            X, g2 + l * DM, be2 + l * DM);
    }

    pool_fc_kernel<<<B_SZ, 128, 0, stream>>>(X, fcw, fcb, d_out, flag);
}